// Round 4
// baseline (310.682 us; speedup 1.0000x reference)
//
#include <hip/hip_runtime.h>
#include <math.h>

// Shapes: B=4, N=16384 (NROW=65536 rows), C=64, K=1024, D1=128, D2=64
#define NROW   65536
#define INV_BN (1.f/65536.f)
#define EPSF   1e-5f

// ------------------------------------------------------------------ k_prep
// per (b,c): g[bc]=mean_k img; dv[bc]=(1/K)sum_k b3[k]*img; MT[b][j][c]=(1/K)sum_k W3[k][j]*img[bc][k]
__global__ __launch_bounds__(256) void k_prep(const float* __restrict__ img,
        const float* __restrict__ W3, const float* __restrict__ b3,
        float* __restrict__ g, float* __restrict__ MT, float* __restrict__ dv) {
    __shared__ float imgs[1024];
    __shared__ float mr[4][64];
    __shared__ float red[256];
    __shared__ float red2[256];
    const int bc = blockIdx.x;
    const int t = threadIdx.x;
    const int b = bc >> 6, c = bc & 63;
    for (int k = t; k < 1024; k += 256) imgs[k] = img[bc*1024 + k];
    __syncthreads();
    const int j = t & 63, kk = t >> 6;
    float a = 0.f;
    #pragma unroll 4
    for (int k = kk*256; k < kk*256 + 256; ++k) a += imgs[k] * W3[k*64 + j];
    mr[kk][j] = a;
    float d = 0.f, s = 0.f;
    #pragma unroll 4
    for (int k = t; k < 1024; k += 256) { d += b3[k]*imgs[k]; s += imgs[k]; }
    red[t] = d; red2[t] = s;
    __syncthreads();
    if (t < 64) MT[(b*64 + t)*64 + c] = (mr[0][t]+mr[1][t]+mr[2][t]+mr[3][t]) * (1.f/1024.f);
    for (int w = 128; w > 0; w >>= 1) {
        if (t < w) { red[t] += red[t+w]; red2[t] += red2[t+w]; }
        __syncthreads();
    }
    if (t == 0) { dv[bc] = red[0]*(1.f/1024.f); g[bc] = red2[0]*(1.f/1024.f); }
}

// ------------------------------------------------------------------ k_wt: weight transposes + c1
__global__ __launch_bounds__(512) void k_wt(const float* __restrict__ W1,
        const float* __restrict__ W2, const float* __restrict__ b1,
        const float* __restrict__ g, float* __restrict__ W1hT,
        float* __restrict__ W2T, float* __restrict__ c1) {
    const int t = threadIdx.x;
    for (int i = t; i < 8192; i += 512) {           // W1hT[c][o] = W1[o][64+c]
        int c = i >> 7, o = i & 127;
        W1hT[i] = W1[o*128 + 64 + c];
    }
    for (int i = t; i < 8192; i += 512) {           // W2T[o][j] = W2[j][o]
        int o = i >> 6, jj = i & 63;
        W2T[i] = W2[jj*128 + o];
    }
    const int b = t >> 7, o = t & 127;              // c1[b][o]
    float s = b1[o];
    #pragma unroll 8
    for (int c = 0; c < 64; ++c) s += g[b*64 + c] * W1[o*128 + c];
    c1[t] = s;
}

// ------------------------------------------------------------------ GEMM1: 64 rows/block, wave owns 32 o-channels
// y1T[o][row] = sum_c lidar[row][c]*W1hT[c][o] + c1[b][o]
__global__ __launch_bounds__(256) void k_gemm1(const float* __restrict__ lidar,
        const float* __restrict__ W1hT, const float* __restrict__ c1,
        float* __restrict__ y1T) {
    __shared__ float Lt[64*65];          // [c][row], pad 65 -> conflict-free
    const int t = threadIdx.x;
    const int base = blockIdx.x * 64;    // 1024 blocks
    const int b = base >> 14;
    const int lane = t & 63;
    const int wo = (t >> 6) * 32;
    for (int i = t; i < 4096; i += 256) {        // coalesced global, conflict-free LDS
        int r = i >> 6, c = i & 63;
        Lt[c*65 + r] = lidar[(base + r)*64 + c];
    }
    __syncthreads();
    float acc[32] = {};
    #pragma unroll 2
    for (int c = 0; c < 64; ++c) {
        float a = Lt[c*65 + lane];
        #pragma unroll
        for (int oi = 0; oi < 32; ++oi)
            acc[oi] += a * W1hT[c*128 + wo + oi];   // wave-uniform -> s_load
    }
    #pragma unroll
    for (int oi = 0; oi < 32; ++oi)
        y1T[(wo + oi)*NROW + base + lane] = acc[oi] + c1[b*128 + wo + oi];
}

// ------------------------------------------------------------------ stats kernels (exact two-pass BN)
__global__ __launch_bounds__(256) void k_st1(const float* __restrict__ y1T, float* __restrict__ st) {
    __shared__ float r1[256], r2[256];
    const int t = threadIdx.x;
    const int o = blockIdx.x >> 2;       // 512 blocks, 128 channels x 4 chunks
    const int q = blockIdx.x & 3;
    const float4* p = (const float4*)(y1T + o*NROW + q*16384);
    float s = 0.f, sq = 0.f;
    #pragma unroll 4
    for (int i = t; i < 4096; i += 256) {
        float4 v = p[i];
        s  += v.x + v.y + v.z + v.w;
        sq += v.x*v.x + v.y*v.y + v.z*v.z + v.w*v.w;
    }
    r1[t] = s; r2[t] = sq; __syncthreads();
    for (int w = 128; w > 0; w >>= 1) {
        if (t < w) { r1[t] += r1[t+w]; r2[t] += r2[t+w]; }
        __syncthreads();
    }
    if (t == 0) { atomicAdd(&st[o], r1[0]); atomicAdd(&st[128 + o], r2[0]); }
}
__global__ __launch_bounds__(256) void k_st2(const float* __restrict__ y2T, float* __restrict__ st2) {
    __shared__ float r1[256], r2[256];
    const int t = threadIdx.x;
    const int o = blockIdx.x >> 3;       // 512 blocks, 64 channels x 8 chunks
    const int q = blockIdx.x & 7;
    const float4* p = (const float4*)(y2T + o*NROW + q*8192);
    float s = 0.f, sq = 0.f;
    #pragma unroll 4
    for (int i = t; i < 2048; i += 256) {
        float4 v = p[i];
        s  += v.x + v.y + v.z + v.w;
        sq += v.x*v.x + v.y*v.y + v.z*v.z + v.w*v.w;
    }
    r1[t] = s; r2[t] = sq; __syncthreads();
    for (int w = 128; w > 0; w >>= 1) {
        if (t < w) { r1[t] += r1[t+w]; r2[t] += r2[t+w]; }
        __syncthreads();
    }
    if (t == 0) { atomicAdd(&st2[o], r1[0]); atomicAdd(&st2[64 + o], r2[0]); }
}

// ------------------------------------------------------------------ k_fin1/k_fin2
__global__ void k_fin1(const float* __restrict__ st, const float* __restrict__ g1,
                       const float* __restrict__ be1, float* __restrict__ sc) {
    const int o = threadIdx.x;  // 128
    float mu = st[o] * INV_BN;
    float var = st[128 + o] * INV_BN - mu*mu;
    float s = g1[o] * rsqrtf(var + EPSF);
    sc[o] = s; sc[128 + o] = be1[o] - mu*s;
}
__global__ void k_fin2(const float* __restrict__ st2, const float* __restrict__ g2,
                       const float* __restrict__ be2, float* __restrict__ sc2) {
    const int o = threadIdx.x;  // 64
    float mu = st2[o] * INV_BN;
    float var = st2[64 + o] * INV_BN - mu*mu;
    float s = g2[o] * rsqrtf(var + EPSF);
    sc2[o] = s; sc2[64 + o] = be2[o] - mu*s;
}

// ------------------------------------------------------------------ GEMM2: 64 rows/block, wave owns 16 j; no LDS, no barriers
// y2T[j][row] = sum_o relu(bn1(y1T[o][row]))*W2T[o][j] + b2[j]
__global__ __launch_bounds__(256) void k_gemm2(const float* __restrict__ y1T,
        const float* __restrict__ W2T, const float* __restrict__ sc,
        const float* __restrict__ b2, float* __restrict__ y2T) {
    const int t = threadIdx.x;
    const int base = blockIdx.x * 64;    // 1024 blocks
    const int lane = t & 63;
    const int wj = (t >> 6) * 16;
    float acc[16] = {};
    #pragma unroll 4
    for (int o = 0; o < 128; ++o) {
        float v = y1T[o*NROW + base + lane];          // coalesced; L1-shared across waves
        v = fmaxf(v * sc[o] + sc[128 + o], 0.f);
        #pragma unroll
        for (int ji = 0; ji < 16; ++ji)
            acc[ji] += v * W2T[o*64 + wj + ji];       // wave-uniform -> s_load
    }
    #pragma unroll
    for (int ji = 0; ji < 16; ++ji)
        y2T[(wj + ji)*NROW + base + lane] = acc[ji] + b2[wj + ji];
}

// ------------------------------------------------------------------ GEMM3: 64 rows/block, wave owns 16 c; LDS only for output transpose
// out[row][c] = sum_j relu(bn2(y2T[j][row]))*MT[b][j][c] + dv[b][c]
__global__ __launch_bounds__(256) void k_gemm3(const float* __restrict__ y2T,
        const float* __restrict__ MT, const float* __restrict__ dv,
        const float* __restrict__ sc2, float* __restrict__ out) {
    __shared__ float Ot[64*65];
    const int t = threadIdx.x;
    const int base = blockIdx.x * 64;    // 1024 blocks
    const int b = base >> 14;
    const int lane = t & 63;
    const int wc = (t >> 6) * 16;
    float acc[16] = {};
    #pragma unroll 4
    for (int j = 0; j < 64; ++j) {
        float v = y2T[j*NROW + base + lane];
        v = fmaxf(v * sc2[j] + sc2[64 + j], 0.f);
        #pragma unroll
        for (int ci = 0; ci < 16; ++ci)
            acc[ci] += v * MT[(b*64 + j)*64 + wc + ci];  // wave-uniform -> s_load
    }
    #pragma unroll
    for (int ci = 0; ci < 16; ++ci)
        Ot[(wc + ci)*65 + lane] = acc[ci] + dv[b*64 + wc + ci];
    __syncthreads();
    for (int i = t; i < 4096; i += 256) {   // coalesced row-major store
        int r = i >> 6, c = i & 63;
        out[(base + r)*64 + c] = Ot[c*65 + r];
    }
}

// ------------------------------------------------------------------
extern "C" void kernel_launch(void* const* d_in, const int* in_sizes, int n_in,
                              void* d_out, int out_size, void* d_ws, size_t ws_size,
                              hipStream_t stream) {
    const float* lidar = (const float*)d_in[0];
    const float* img   = (const float*)d_in[1];
    const float* W1  = (const float*)d_in[2];
    const float* b1  = (const float*)d_in[3];
    const float* g1  = (const float*)d_in[4];
    const float* be1 = (const float*)d_in[5];
    const float* W2  = (const float*)d_in[6];
    const float* b2  = (const float*)d_in[7];
    const float* g2  = (const float*)d_in[8];
    const float* be2 = (const float*)d_in[9];
    const float* W3  = (const float*)d_in[10];
    const float* b3  = (const float*)d_in[11];

    float* ws   = (float*)d_ws;
    float* y1T  = ws;                    // 128*65536
    float* y2T  = y1T + 128*NROW;        // 64*65536
    float* g    = y2T + 64*NROW;         // 256
    float* c1   = g   + 256;             // 512
    float* MT   = c1  + 512;             // 16384
    float* dv   = MT  + 16384;           // 256
    float* W1hT = dv  + 256;             // 8192
    float* W2T  = W1hT + 8192;           // 8192
    float* st   = W2T + 8192;            // 384
    float* sc   = st  + 384;             // 384

    hipMemsetAsync(st, 0, 384 * sizeof(float), stream);

    k_prep <<<256,  256, 0, stream>>>(img, W3, b3, g, MT, dv);
    k_wt   <<<1,    512, 0, stream>>>(W1, W2, b1, g, W1hT, W2T, c1);
    k_gemm1<<<1024, 256, 0, stream>>>(lidar, W1hT, c1, y1T);
    k_st1  <<<512,  256, 0, stream>>>(y1T, st);
    k_fin1 <<<1,    128, 0, stream>>>(st, g1, be1, sc);
    k_gemm2<<<1024, 256, 0, stream>>>(y1T, W2T, sc, b2, y2T);
    k_st2  <<<512,  256, 0, stream>>>(y2T, st + 256);
    k_fin2 <<<1,    64,  0, stream>>>(st + 256, g2, be2, sc + 256);
    k_gemm3<<<1024, 256, 0, stream>>>(y2T, MT, dv, sc + 256, (float*)d_out);
}

// Round 5
// 214.352 us; speedup vs baseline: 1.4494x; 1.4494x over previous
//
#include <hip/hip_runtime.h>
#include <math.h>

// Shapes: B=4, N=16384 (NROW=65536 rows), C=64, K=1024, D1=128, D2=64
#define NROW   65536
#define INV_BN (1.f/65536.f)
#define EPSF   1e-5f

// ------------------------------------------------------------------ k_prep
// per (b,c): g[bc]=mean_k img; dv[bc]=(1/K)sum_k b3[k]*img; MT[b][j][c]=(1/K)sum_k W3[k][j]*img[bc][k]
__global__ __launch_bounds__(256) void k_prep(const float* __restrict__ img,
        const float* __restrict__ W3, const float* __restrict__ b3,
        float* __restrict__ g, float* __restrict__ MT, float* __restrict__ dv) {
    __shared__ float imgs[1024];
    __shared__ float mr[4][64];
    __shared__ float red[256];
    __shared__ float red2[256];
    const int bc = blockIdx.x;
    const int t = threadIdx.x;
    const int b = bc >> 6, c = bc & 63;
    for (int k = t; k < 1024; k += 256) imgs[k] = img[bc*1024 + k];
    __syncthreads();
    const int j = t & 63, kk = t >> 6;
    float a = 0.f;
    #pragma unroll 4
    for (int k = kk*256; k < kk*256 + 256; ++k) a += imgs[k] * W3[k*64 + j];
    mr[kk][j] = a;
    float d = 0.f, s = 0.f;
    #pragma unroll 4
    for (int k = t; k < 1024; k += 256) { d += b3[k]*imgs[k]; s += imgs[k]; }
    red[t] = d; red2[t] = s;
    __syncthreads();
    if (t < 64) MT[(b*64 + t)*64 + c] = (mr[0][t]+mr[1][t]+mr[2][t]+mr[3][t]) * (1.f/1024.f);
    for (int w = 128; w > 0; w >>= 1) {
        if (t < w) { red[t] += red[t+w]; red2[t] += red2[t+w]; }
        __syncthreads();
    }
    if (t == 0) { dv[bc] = red[0]*(1.f/1024.f); g[bc] = red2[0]*(1.f/1024.f); }
}

// ------------------------------------------------------------------ k_wt: weight transposes + c1
__global__ __launch_bounds__(512) void k_wt(const float* __restrict__ W1,
        const float* __restrict__ W2, const float* __restrict__ b1,
        const float* __restrict__ g, float* __restrict__ W1hT,
        float* __restrict__ W2T, float* __restrict__ c1) {
    const int t = threadIdx.x;
    for (int i = t; i < 8192; i += 512) {           // W1hT[c][o] = W1[o][64+c]
        int c = i >> 7, o = i & 127;
        W1hT[i] = W1[o*128 + 64 + c];
    }
    for (int i = t; i < 8192; i += 512) {           // W2T[o][j] = W2[j][o]
        int o = i >> 6, jj = i & 63;
        W2T[i] = W2[jj*128 + o];
    }
    const int b = t >> 7, o = t & 127;              // c1[b][o]
    float s = b1[o];
    #pragma unroll 8
    for (int c = 0; c < 64; ++c) s += g[b*64 + c] * W1[o*128 + c];
    c1[t] = s;
}

// ------------------------------------------------------------------ k_tr: lidarT[c][row] = lidar[row][c]
__global__ __launch_bounds__(256) void k_tr(const float* __restrict__ lidar,
                                            float* __restrict__ lidarT) {
    __shared__ float T[64*65];
    const int t = threadIdx.x;
    const int base = blockIdx.x * 64;   // 1024 blocks
    for (int i = t; i < 4096; i += 256) {
        int r = i >> 6, c = i & 63;
        T[c*65 + r] = lidar[(base + r)*64 + c];       // coalesced read
    }
    __syncthreads();
    for (int i = t; i < 4096; i += 256) {
        int c = i >> 6, r = i & 63;
        lidarT[c*NROW + base + r] = T[c*65 + r];      // coalesced write
    }
}

// ------------------------------------------------------------------ GEMM1: lane=row, wave=16 o-chans, W in LDS
// y1T[o][row] = sum_c lidarT[c][row]*W1hT[c][o] + c1[b][o]
__global__ __launch_bounds__(256) void k_gemm1(const float* __restrict__ lidarT,
        const float* __restrict__ W1hT, const float* __restrict__ c1,
        float* __restrict__ y1T) {
    __shared__ __align__(16) float Wl[64*64];        // [c][o-go], 16 KB
    const int t = threadIdx.x;
    const int base = blockIdx.x * 64;                // grid (1024, 2)
    const int go = blockIdx.y * 64;
    const int b = blockIdx.x >> 8;
    for (int i = t; i < 4096; i += 256) {
        int c = i >> 6, o = i & 63;
        Wl[i] = W1hT[c*128 + go + o];
    }
    __syncthreads();
    const int lane = t & 63;
    const int wo = (t >> 6) * 16;
    const float* ap = lidarT + base + lane;
    float acc[16] = {};
    #pragma unroll 4
    for (int c = 0; c < 64; ++c) {
        float a = ap[c*NROW];                         // coalesced global
        float wv[16];
        *(float4*)&wv[0]  = *(const float4*)&Wl[c*64 + wo];      // uniform ds_read_b128
        *(float4*)&wv[4]  = *(const float4*)&Wl[c*64 + wo + 4];
        *(float4*)&wv[8]  = *(const float4*)&Wl[c*64 + wo + 8];
        *(float4*)&wv[12] = *(const float4*)&Wl[c*64 + wo + 12];
        #pragma unroll
        for (int ji = 0; ji < 16; ++ji) acc[ji] += a * wv[ji];
    }
    #pragma unroll
    for (int ji = 0; ji < 16; ++ji)
        y1T[(go + wo + ji)*NROW + base + lane] = acc[ji] + c1[b*128 + go + wo + ji];
}

// ------------------------------------------------------------------ stats kernels (exact two-pass BN)
__global__ __launch_bounds__(256) void k_st1(const float* __restrict__ y1T, float* __restrict__ st) {
    __shared__ float r1[256], r2[256];
    const int t = threadIdx.x;
    const int o = blockIdx.x >> 2;       // 512 blocks, 128 channels x 4 chunks
    const int q = blockIdx.x & 3;
    const float4* p = (const float4*)(y1T + o*NROW + q*16384);
    float s = 0.f, sq = 0.f;
    #pragma unroll 4
    for (int i = t; i < 4096; i += 256) {
        float4 v = p[i];
        s  += v.x + v.y + v.z + v.w;
        sq += v.x*v.x + v.y*v.y + v.z*v.z + v.w*v.w;
    }
    r1[t] = s; r2[t] = sq; __syncthreads();
    for (int w = 128; w > 0; w >>= 1) {
        if (t < w) { r1[t] += r1[t+w]; r2[t] += r2[t+w]; }
        __syncthreads();
    }
    if (t == 0) { atomicAdd(&st[o], r1[0]); atomicAdd(&st[128 + o], r2[0]); }
}
__global__ __launch_bounds__(256) void k_st2(const float* __restrict__ y2T, float* __restrict__ st2) {
    __shared__ float r1[256], r2[256];
    const int t = threadIdx.x;
    const int o = blockIdx.x >> 3;       // 512 blocks, 64 channels x 8 chunks
    const int q = blockIdx.x & 7;
    const float4* p = (const float4*)(y2T + o*NROW + q*8192);
    float s = 0.f, sq = 0.f;
    #pragma unroll 4
    for (int i = t; i < 2048; i += 256) {
        float4 v = p[i];
        s  += v.x + v.y + v.z + v.w;
        sq += v.x*v.x + v.y*v.y + v.z*v.z + v.w*v.w;
    }
    r1[t] = s; r2[t] = sq; __syncthreads();
    for (int w = 128; w > 0; w >>= 1) {
        if (t < w) { r1[t] += r1[t+w]; r2[t] += r2[t+w]; }
        __syncthreads();
    }
    if (t == 0) { atomicAdd(&st2[o], r1[0]); atomicAdd(&st2[64 + o], r2[0]); }
}

// ------------------------------------------------------------------ k_fin1/k_fin2
__global__ void k_fin1(const float* __restrict__ st, const float* __restrict__ g1,
                       const float* __restrict__ be1, float* __restrict__ sc) {
    const int o = threadIdx.x;  // 128
    float mu = st[o] * INV_BN;
    float var = st[128 + o] * INV_BN - mu*mu;
    float s = g1[o] * rsqrtf(var + EPSF);
    sc[o] = s; sc[128 + o] = be1[o] - mu*s;
}
__global__ void k_fin2(const float* __restrict__ st2, const float* __restrict__ g2,
                       const float* __restrict__ be2, float* __restrict__ sc2) {
    const int o = threadIdx.x;  // 64
    float mu = st2[o] * INV_BN;
    float var = st2[64 + o] * INV_BN - mu*mu;
    float s = g2[o] * rsqrtf(var + EPSF);
    sc2[o] = s; sc2[64 + o] = be2[o] - mu*s;
}

// ------------------------------------------------------------------ GEMM2: lane=row, wave=16 j, W in LDS
// y2T[j][row] = sum_o relu(bn1(y1T[o][row]))*W2T[o][j] + b2[j]
__global__ __launch_bounds__(256) void k_gemm2(const float* __restrict__ y1T,
        const float* __restrict__ W2T, const float* __restrict__ sc,
        const float* __restrict__ b2, float* __restrict__ y2T) {
    __shared__ __align__(16) float Wl[128*64];       // 32 KB
    const int t = threadIdx.x;
    const int base = blockIdx.x * 64;                // 1024 blocks
    for (int i = t; i < 2048; i += 256)
        *(float4*)&Wl[i*4] = *(const float4*)&W2T[i*4];
    __syncthreads();
    const int lane = t & 63;
    const int wj = (t >> 6) * 16;
    const float* ap = y1T + base + lane;
    float acc[16] = {};
    #pragma unroll 4
    for (int o = 0; o < 128; ++o) {
        float v = ap[o*NROW];                         // coalesced global
        v = fmaxf(fmaf(v, sc[o], sc[128 + o]), 0.f);  // bn1 + relu
        float wv[16];
        *(float4*)&wv[0]  = *(const float4*)&Wl[o*64 + wj];
        *(float4*)&wv[4]  = *(const float4*)&Wl[o*64 + wj + 4];
        *(float4*)&wv[8]  = *(const float4*)&Wl[o*64 + wj + 8];
        *(float4*)&wv[12] = *(const float4*)&Wl[o*64 + wj + 12];
        #pragma unroll
        for (int ji = 0; ji < 16; ++ji) acc[ji] += v * wv[ji];
    }
    #pragma unroll
    for (int ji = 0; ji < 16; ++ji)
        y2T[(wj + ji)*NROW + base + lane] = acc[ji] + b2[wj + ji];
}

// ------------------------------------------------------------------ GEMM3: lane=row, wave=16 c, M in LDS; LDS out-transpose
// out[row][c] = sum_j relu(bn2(y2T[j][row]))*MT[b][j][c] + dv[b][c]
__global__ __launch_bounds__(256) void k_gemm3(const float* __restrict__ y2T,
        const float* __restrict__ MT, const float* __restrict__ dv,
        const float* __restrict__ sc2, float* __restrict__ out) {
    __shared__ __align__(16) float Ml[64*64];        // 16 KB
    __shared__ float Ot[64*65];                      // 16.6 KB
    const int t = threadIdx.x;
    const int base = blockIdx.x * 64;                // 1024 blocks
    const int b = blockIdx.x >> 8;
    for (int i = t; i < 1024; i += 256)
        *(float4*)&Ml[i*4] = *(const float4*)&MT[b*4096 + i*4];
    __syncthreads();
    const int lane = t & 63;
    const int wc = (t >> 6) * 16;
    const float* ap = y2T + base + lane;
    float acc[16] = {};
    #pragma unroll 4
    for (int j = 0; j < 64; ++j) {
        float v = ap[j*NROW];
        v = fmaxf(fmaf(v, sc2[j], sc2[64 + j]), 0.f); // bn2 + relu
        float wv[16];
        *(float4*)&wv[0]  = *(const float4*)&Ml[j*64 + wc];
        *(float4*)&wv[4]  = *(const float4*)&Ml[j*64 + wc + 4];
        *(float4*)&wv[8]  = *(const float4*)&Ml[j*64 + wc + 8];
        *(float4*)&wv[12] = *(const float4*)&Ml[j*64 + wc + 12];
        #pragma unroll
        for (int ci = 0; ci < 16; ++ci) acc[ci] += v * wv[ci];
    }
    #pragma unroll
    for (int ci = 0; ci < 16; ++ci)
        Ot[(wc + ci)*65 + lane] = acc[ci] + dv[b*64 + wc + ci];
    __syncthreads();
    for (int i = t; i < 4096; i += 256) {            // coalesced row-major store
        int r = i >> 6, c = i & 63;
        out[(base + r)*64 + c] = Ot[c*65 + r];
    }
}

// ------------------------------------------------------------------
extern "C" void kernel_launch(void* const* d_in, const int* in_sizes, int n_in,
                              void* d_out, int out_size, void* d_ws, size_t ws_size,
                              hipStream_t stream) {
    const float* lidar = (const float*)d_in[0];
    const float* img   = (const float*)d_in[1];
    const float* W1  = (const float*)d_in[2];
    const float* b1  = (const float*)d_in[3];
    const float* g1  = (const float*)d_in[4];
    const float* be1 = (const float*)d_in[5];
    const float* W2  = (const float*)d_in[6];
    const float* b2  = (const float*)d_in[7];
    const float* g2  = (const float*)d_in[8];
    const float* be2 = (const float*)d_in[9];
    const float* W3  = (const float*)d_in[10];
    const float* b3  = (const float*)d_in[11];

    float* ws     = (float*)d_ws;
    float* y1T    = ws;                    // 128*65536
    float* y2T    = y1T + 128*NROW;        // 64*65536
    float* g      = y2T + 64*NROW;         // 256
    float* c1     = g   + 256;             // 512
    float* MT     = c1  + 512;             // 16384
    float* dv     = MT  + 16384;           // 256
    float* W1hT   = dv  + 256;             // 8192
    float* W2T    = W1hT + 8192;           // 8192
    float* st     = W2T + 8192;            // 384
    float* sc     = st  + 384;             // 384
    float* lidarT = sc  + 384;             // 64*65536

    hipMemsetAsync(st, 0, 384 * sizeof(float), stream);

    k_prep <<<256,  256, 0, stream>>>(img, W3, b3, g, MT, dv);
    k_wt   <<<1,    512, 0, stream>>>(W1, W2, b1, g, W1hT, W2T, c1);
    k_tr   <<<1024, 256, 0, stream>>>(lidar, lidarT);
    k_gemm1<<<dim3(1024,2), 256, 0, stream>>>(lidarT, W1hT, c1, y1T);
    k_st1  <<<512,  256, 0, stream>>>(y1T, st);
    k_fin1 <<<1,    128, 0, stream>>>(st, g1, be1, sc);
    k_gemm2<<<1024, 256, 0, stream>>>(y1T, W2T, sc, b2, y2T);
    k_st2  <<<512,  256, 0, stream>>>(y2T, st + 256);
    k_fin2 <<<1,    64,  0, stream>>>(st + 256, g2, be2, sc + 256);
    k_gemm3<<<1024, 256, 0, stream>>>(y2T, MT, dv, sc + 256, (float*)d_out);
}